// Round 6
// baseline (324.735 us; speedup 1.0000x reference)
//
#include <hip/hip_runtime.h>
#include <math.h>

#define NSTEPS 6
#define DT_ 0.2f
#define LN  64           // lanes per wave = extended rows per band (lane = row)
#define TYN 16           // waves per block = column chunks of 16 (covers 256 cols)
#define NC  4            // float4 groups per thread -> 16 columns per lane
#define GHOST 5
#define INTERIOR (LN - 2*GHOST)   // 54 valid interior rows per band
#define HH 256
#define WW 256
#define NB ((HH + INTERIOR - 1)/INTERIOR)  // 5 bands

// DPP wave-wide shifts (GFX9 lineage). lane=row here:
// rowup: lane i <- lane i-1 (row above), 0x138 = wave_shr:1
// rowdn: lane i <- lane i+1 (row below), 0x130 = wave_shl:1
// bound_ctrl=1 -> edge lanes read 0. Edge lanes are outermost ghost rows whose
// values are dead by the validity schedule (ghost row at distance d from the
// interior only needs to be correct through step 6-d; step 1 is analytic).
__device__ __forceinline__ float rowup(float x){
  return __int_as_float(__builtin_amdgcn_update_dpp(
      0, __float_as_int(x), 0x138, 0xF, 0xF, true));
}
__device__ __forceinline__ float rowdn(float x){
  return __int_as_float(__builtin_amdgcn_update_dpp(
      0, __float_as_int(x), 0x130, 0xF, 0xF, true));
}

// Force a wave-uniform float into an SGPR (frees a VGPR; every consumer is a
// v_fma/v_mul with at most this one scalar operand -> legal encoding).
__device__ __forceinline__ float sconst(float x){
  return __int_as_float(__builtin_amdgcn_readfirstlane(__float_as_int(x)));
}

// One tap-row of the 3x3 conv over 4 consecutive columns.
// out col c gets t0*in[c-1] + t1*in[c] + t2*in[c+1]; lw = col c0-1, rx = col c0+4.
__device__ __forceinline__ void conv_row(const float4 q, float lw, float rx,
                                         float t0, float t1, float t2, float4& acc){
  acc.x = fmaf(t0, lw , fmaf(t1, q.x, fmaf(t2, q.y, acc.x)));
  acc.y = fmaf(t0, q.x, fmaf(t1, q.y, fmaf(t2, q.z, acc.y)));
  acc.z = fmaf(t0, q.y, fmaf(t1, q.z, fmaf(t2, q.w, acc.z)));
  acc.w = fmaf(t0, q.z, fmaf(t1, q.w, fmaf(t2, rx , acc.w)));
}

// NO min-waves clause (rounds 1-2: forcing it spilled the state arrays).
__global__ __launch_bounds__(LN*TYN) void vib6_t(
    const float* __restrict__ force, const float* __restrict__ cw,
    const float* __restrict__ omega, const float* __restrict__ zeta,
    float* __restrict__ out)
{
  const int lane = threadIdx.x;     // 0..63: extended row index within band
  const int ty   = threadIdx.y;     // 0..15: column chunk (cols 16*ty .. 16*ty+15)
  const int band = blockIdx.x;      // 0..NB-1
  const int plane= blockIdx.y;      // b*64 + c
  const int ch = plane & 63;

  // per-channel uniform constants -> SGPRs
  const float om = omega[ch], ze = zeta[ch];
  const float w   = log1pf(expf(om));          // softplus
  const float z   = 1.f/(1.f + expf(-ze));     // sigmoid
  const float w2  = w*w;
  const float aco = sconst(1.f - 2.f*z*w*DT_); // v' = aco*v + bco*x + DT*(f+inter)
  const float bco = sconst(-w2*DT_);
  const float w2h = sconst(0.5f*w2);
  float wdt[9];
  #pragma unroll
  for (int k=0;k<9;++k) wdt[k] = sconst(DT_*cw[ch*9+k]);  // DT folded into taps

  // double-buffered horizontal edge-column exchange (2 floats/thread/step)
  __shared__ float ledge[2][TYN][LN];   // wave ty's col 16*ty   (left edge)
  __shared__ float redge[2][TYN][LN];   // wave ty's col 16*ty+15 (right edge)

  const int c0 = ty*16;
  const int g  = band*INTERIOR - GHOST + lane;   // global image row of this lane
  const bool inimg = (g>=0) && (g<HH);
  const float msk = inimg ? 1.f : 0.f;           // per-lane: image zero-padding rows
  const size_t pbase = (size_t)plane*(HH*WW);

  float4 x[NC], v[NC], F[NC];

  // ---- load force (DT-prescaled), step 1 analytically ----
  #pragma unroll
  for (int i=0;i<NC;++i){
    float4 f4 = make_float4(0.f,0.f,0.f,0.f);
    if (inimg) f4 = *(const float4*)(force + pbase + (size_t)g*WW + c0 + 4*i);
    F[i].x = DT_*f4.x; F[i].y = DT_*f4.y; F[i].z = DT_*f4.z; F[i].w = DT_*f4.w;
    v[i] = F[i];   // v1 = DT*f (conv(x0)=0); OOB rows: f=0 -> stays 0
    x[i].x = DT_*F[i].x; x[i].y = DT_*F[i].y; x[i].z = DT_*F[i].z; x[i].w = DT_*F[i].w;
  }

  // seed edge buffers for first loop iteration (reads buf[1])
  ledge[1][ty][lane] = x[0].x;
  redge[1][ty][lane] = x[NC-1].w;

  // ---- steps 2..6 ----
  #pragma unroll
  for (int s=1; s<NSTEPS; ++s){
    const int p = s & 1;
    __syncthreads();
    // neighbor waves' edge columns (previous-step x); image L/R edges -> 0 pad
    const float lcol = (ty>0)     ? redge[p][ty-1][lane] : 0.f;
    const float rcol = (ty<TYN-1) ? ledge[p][ty+1][lane] : 0.f;

    // left-column triple for group 0 (row-above / row / row-below)
    float lu = rowup(lcol), lc = lcol, ld = rowdn(lcol);

    #pragma unroll
    for (int gi=0; gi<NC; ++gi){
      const float4 xc = x[gi];          // old x (pre-update), this lane's row
      float4 xu, xd;                    // rows above/below via DPP (old values:
      xu.x = rowup(xc.x); xu.y = rowup(xc.y);   // all reads of x[gi] happen
      xu.z = rowup(xc.z); xu.w = rowup(xc.w);   // before any lane FINs it —
      xd.x = rowdn(xc.x); xd.y = rowdn(xc.y);   // lockstep within the wave)
      xd.z = rowdn(xc.z); xd.w = rowdn(xc.w);
      // right-column triple: next group's first col (old) or LDS edge
      const float rc = (gi < NC-1) ? x[gi+1].x : rcol;
      const float ru = rowup(rc), rd = rowdn(rc);

      float4 acc = F[gi];               // seed with DT*f
      conv_row(xu, lu, ru, wdt[0], wdt[1], wdt[2], acc);  // tap row -1
      conv_row(xc, lc, rc, wdt[3], wdt[4], wdt[5], acc);  // tap row  0
      conv_row(xd, ld, rd, wdt[6], wdt[7], wdt[8], acc);  // tap row +1

      // carry old right edge of this group as next group's left triple
      lu = xu.w; lc = xc.w; ld = xd.w;

      // finalize: v' = aco*v + bco*x + acc ; x' = (x + DT*v')*msk
      v[gi].x = fmaf(aco, v[gi].x, fmaf(bco, x[gi].x, acc.x));
      v[gi].y = fmaf(aco, v[gi].y, fmaf(bco, x[gi].y, acc.y));
      v[gi].z = fmaf(aco, v[gi].z, fmaf(bco, x[gi].z, acc.z));
      v[gi].w = fmaf(aco, v[gi].w, fmaf(bco, x[gi].w, acc.w));
      x[gi].x = fmaf(DT_, v[gi].x, x[gi].x) * msk;
      x[gi].y = fmaf(DT_, v[gi].y, x[gi].y) * msk;
      x[gi].z = fmaf(DT_, v[gi].z, x[gi].z) * msk;
      x[gi].w = fmaf(DT_, v[gi].w, x[gi].w) * msk;

      // publish new edge columns early (hides ds_write under remaining groups)
      if (s < NSTEPS-1){
        if (gi == 0)    ledge[p^1][ty][lane] = x[0].x;
        if (gi == NC-1) redge[p^1][ty][lane] = x[NC-1].w;
      }
    }
  }

  // ---- epilogue: out = 0.5 v^2 + 0.5 w^2 x^2 on interior lanes ----
  if (lane >= GHOST && lane < LN-GHOST && inimg){
    #pragma unroll
    for (int i=0;i<NC;++i){
      float4 o;
      o.x = fmaf(0.5f*v[i].x, v[i].x, w2h*x[i].x*x[i].x);
      o.y = fmaf(0.5f*v[i].y, v[i].y, w2h*x[i].y*x[i].y);
      o.z = fmaf(0.5f*v[i].z, v[i].z, w2h*x[i].z*x[i].z);
      o.w = fmaf(0.5f*v[i].w, v[i].w, w2h*x[i].w*x[i].w);
      *(float4*)(out + pbase + (size_t)g*WW + c0 + 4*i) = o;
    }
  }
}

extern "C" void kernel_launch(void* const* d_in, const int* in_sizes, int n_in,
                              void* d_out, int out_size, void* d_ws, size_t ws_size,
                              hipStream_t stream) {
  const float* force = (const float*)d_in[0];   // [8,64,256,256]
  const float* cw    = (const float*)d_in[1];   // [64,1,3,3]
  const float* om    = (const float*)d_in[2];   // [64]
  const float* ze    = (const float*)d_in[3];   // [64]
  float* out = (float*)d_out;                   // [8,64,256,256]
  dim3 grid(NB, 8*64);
  dim3 block(LN, TYN);
  hipLaunchKernelGGL(vib6_t, grid, block, 0, stream, force, cw, om, ze, out);
}